// Round 5
// baseline (75.204 us; speedup 1.0000x reference)
//
#include <hip/hip_runtime.h>

// Problem: B=16,H=16,P=128,D=128,NF=12
// rows per branch = B*H*P = 32768; total rows (q then k) = 65536.
//
// R5 structure: 128-row blocks, 8 waves, LDS = 64KB exactly.
//   phase 1: stage W bf16 [128][128] (block-wide) + silu(x) bf16 (wave-own rows)
//   barrier; phase 2: MFMA (wave: 16 rows x 128 cols); barrier
//   phase 3: acc -> F f32 [128][128] overlaying dead W+A (parity col-swizzle)
//   phase 4: wave-private epilogue (Chebyshev sin basis + sigmoid + row-sum),
//            no further barriers.
//
// ws layout (floats):
//   sums: [0, 65536)   R: [65536, 65664)   T: [65664, 98432)
//   wbf:  [98432, ...) base_weight bf16 bits (16384 ushorts)

typedef float          f32x4 __attribute__((ext_vector_type(4)));
typedef short          s16x8 __attribute__((ext_vector_type(8)));
typedef unsigned short u16x8 __attribute__((ext_vector_type(8)));

static __device__ __forceinline__ unsigned short f2bf(float f) {
    unsigned int u = __float_as_uint(f);
    u += 0x7FFFu + ((u >> 16) & 1u);       // round-to-nearest-even
    return (unsigned short)(u >> 16);
}
// XOR swizzle for [row][256B] bf16 LDS tiles read 16B/lane (G4 pattern)
static __device__ __forceinline__ int swz(int local) {
    return local ^ (((local >> 8) & 7) << 4);
}

__global__ __launch_bounds__(256) void k_convert(const float* __restrict__ bw,
                                                 unsigned short* __restrict__ wbf) {
    int i = blockIdx.x * 256 + threadIdx.x;
    if (i < 128 * 128) wbf[i] = f2bf(bw[i]);
}

__global__ __launch_bounds__(512, 4) void k_branch(
    const float* __restrict__ q, const float* __restrict__ k,
    const unsigned short* __restrict__ wbf,   // base_weight bf16 [d][e] (= B[n][k])
    const float* __restrict__ gridv,          // [12], == 1..12
    const float* __restrict__ coef_q, const float* __restrict__ coef_k,
    const float* __restrict__ sbase,          // scale_base (1,H,P,D)
    const float* __restrict__ ssp,            // scale_sp   (1,H,P,D)
    float* __restrict__ sums)
{
    __shared__ char smem[65536];
    // [0,32768): W bf16 swizzled; [32768,65536): A bf16 swizzled
    // after MFMA: F f32 [128][128] overlays everything
    float* F_l = (float*)smem;

    const int t = threadIdx.x;
    const int lane = t & 63, w = t >> 6;        // 8 waves
    const int r15 = lane & 15, g4 = lane >> 4;
    const int row0 = blockIdx.x * 128;
    const bool is_q = row0 < 32768;
    const float* X = is_q ? q : k;
    const float* coef = is_q ? coef_q : coef_k;
    const int xrow0 = is_q ? row0 : row0 - 32768;

    // ---- phase 1a: stage W bf16 (block-wide, 4 x 16B per thread) ----
    #pragma unroll
    for (int it = 0; it < 4; ++it) {
        int c = it * 512 + t;                       // 0..2047 chunks
        u16x8 v = *(const u16x8*)&wbf[c * 8];
        *(u16x8*)(smem + swz(c * 16)) = v;
    }
    // ---- phase 1b: stage silu(x) bf16, wave-own rows (4 x 8 el per thread) ----
    #pragma unroll
    for (int it = 0; it < 4; ++it) {
        int row = w * 16 + it * 4 + g4;             // wave-private rows
        const float4* xp = (const float4*)&X[(xrow0 + row) * 128 + r15 * 8];
        float4 x0 = xp[0], x1 = xp[1];
        float xs[8] = {x0.x, x0.y, x0.z, x0.w, x1.x, x1.y, x1.z, x1.w};
        u16x8 sv;
        #pragma unroll
        for (int j = 0; j < 8; ++j) {
            float s = xs[j] / (1.f + __expf(-xs[j]));   // silu
            sv[j] = f2bf(s);
        }
        *(u16x8*)(smem + swz(32768 + row * 256 + r15 * 16)) = sv;
    }
    __syncthreads();

    // ---- phase 2: MFMA  out[m][n] = sum_k silu(x)[m][k] * W[n][k] ----
    f32x4 acc[8];
    #pragma unroll
    for (int n = 0; n < 8; ++n) acc[n] = (f32x4){0.f, 0.f, 0.f, 0.f};

    const int abase = 32768 + (w * 16 + r15) * 256 + g4 * 16;  // A row = m
    const int bbase = r15 * 256 + g4 * 16;                     // W row = n
    #pragma unroll
    for (int s = 0; s < 4; ++s) {                              // k-steps of 32
        s16x8 af = *(const s16x8*)(smem + swz(abase + s * 64));
        #pragma unroll
        for (int n = 0; n < 8; ++n) {
            s16x8 bf = *(const s16x8*)(smem + swz(bbase + n * 4096 + s * 64));
            acc[n] = __builtin_amdgcn_mfma_f32_16x16x32_bf16(af, bf, acc[n], 0, 0, 0);
        }
    }
    __syncthreads();   // all waves done reading W/A; F may now overlay

    // ---- phase 3: acc -> F_l (wave-private rows; parity col-swizzle) ----
    // element (row,col) stored at float idx row*128 + (col ^ (4*(row&1)))
    #pragma unroll
    for (int n = 0; n < 8; ++n) {
        int col = n * 16 + r15;
        #pragma unroll
        for (int reg = 0; reg < 4; ++reg) {
            int row = w * 16 + g4 * 4 + reg;
            F_l[row * 128 + (col ^ ((row & 1) << 2))] = acc[n][reg];
        }
    }
    // no barrier: each wave reads back only its own rows (DS is in-order per wave)

    // ---- phase 4: epilogue, wave-private rows ----
    const float g1 = gridv[0];   // == 1.0; basis freqs are g1*(1..12)

    #pragma unroll
    for (int it = 0; it < 4; ++it) {
        int row = w * 16 + it * 4 + g4;
        int p = row & 1;
        int hp = (row0 + row) & 2047;
        const float4* Fb = (const float4*)F_l + row * 32 + r15 * 2;
        float4 F0 = Fb[p], F1 = Fb[1 - p];          // cols r15*8..+3, +4..+7
        const float4* xp = (const float4*)&X[(xrow0 + row) * 128 + r15 * 8];
        float4 x0 = xp[0], x1 = xp[1];
        const float4* pp = (const float4*)&ssp[hp * 128 + r15 * 8];
        float4 p0 = pp[0], p1 = pp[1];
        const float4* bp = (const float4*)&sbase[hp * 128 + r15 * 8];
        float4 b0 = bp[0], b1 = bp[1];
        float Fv[8] = {F0.x, F0.y, F0.z, F0.w, F1.x, F1.y, F1.z, F1.w};
        float xs[8] = {x0.x, x0.y, x0.z, x0.w, x1.x, x1.y, x1.z, x1.w};
        float pv[8] = {p0.x, p0.y, p0.z, p0.w, p1.x, p1.y, p1.z, p1.w};
        float bv[8] = {b0.x, b0.y, b0.z, b0.w, b1.x, b1.y, b1.z, b1.w};
        float ps = 0.f;
        #pragma unroll
        for (int j = 0; j < 8; ++j) {
            int col = r15 * 8 + j;
            const float4* cp = (const float4*)&coef[col * 12];
            float4 c0 = cp[0], c1 = cp[1], c2 = cp[2];
            float cf[12] = {c0.x, c0.y, c0.z, c0.w, c1.x, c1.y, c1.z, c1.w,
                            c2.x, c2.y, c2.z, c2.w};
            float a = g1 * xs[j];
            float s1, cv;
            __sincosf(a, &s1, &cv);
            float t2 = cv + cv;
            float sprev = 0.f, scur = s1;
            float f = cf[0] * s1;
            #pragma unroll
            for (int u = 1; u < 12; ++u) {
                float snext = __builtin_fmaf(t2, scur, -sprev);
                f = __builtin_fmaf(cf[u], snext, f);
                sprev = scur; scur = snext;
            }
            float z = f * pv[j] + Fv[j] * bv[j];
            ps += 1.f / (1.f + __expf(-z));
        }
        // reduce over r15 (16 lanes share this row)
        ps += __shfl_xor(ps, 1, 64);
        ps += __shfl_xor(ps, 2, 64);
        ps += __shfl_xor(ps, 4, 64);
        ps += __shfl_xor(ps, 8, 64);
        if (r15 == 0) sums[row0 + row] = ps;
    }
}

// T[bh][j] = sum_p sk[bh][p]*w_qk[j][p] + b_qk[j]; block 256 computes R[j].
__global__ __launch_bounds__(128) void k_tvec(
    const float* __restrict__ sums, const float* __restrict__ w_qk,
    const float* __restrict__ b_qk, float* __restrict__ T, float* __restrict__ R)
{
    __shared__ float skl[128];
    int bh = blockIdx.x;
    int t = threadIdx.x;
    const float4* wr = (const float4*)&w_qk[t * 128];
    if (bh < 256) {
        skl[t] = sums[32768 + bh * 128 + t];
        __syncthreads();
        float a = 0.f;
        #pragma unroll 8
        for (int p4 = 0; p4 < 32; ++p4) {
            float4 w4 = wr[p4];
            a += w4.x * skl[p4 * 4 + 0] + w4.y * skl[p4 * 4 + 1] +
                 w4.z * skl[p4 * 4 + 2] + w4.w * skl[p4 * 4 + 3];
        }
        T[bh * 128 + t] = a + b_qk[t];
    } else {
        float a = 0.f;
        #pragma unroll 8
        for (int p4 = 0; p4 < 32; ++p4) {
            float4 w4 = wr[p4];
            a += w4.x + w4.y + w4.z + w4.w;
        }
        R[t] = a;
    }
}

// Softmax over j: logit[j] = sq[row]*R[j] + T[bh][j]. One wave per row.
// Lane handles cols 2*lane, 2*lane+1 -> float2-coalesced loads/stores.
__global__ __launch_bounds__(256) void k_softmax(
    const float* __restrict__ sums, const float* __restrict__ T,
    const float* __restrict__ R, float* __restrict__ out)
{
    int row = blockIdx.x * 4 + (threadIdx.x >> 6);
    int lane = threadIdx.x & 63;
    int bh = row >> 7;
    float sqv = sums[row];
    float2 r2 = *(const float2*)&R[lane * 2];
    float2 t2 = *(const float2*)&T[bh * 128 + lane * 2];
    float l0 = sqv * r2.x + t2.x;
    float l1 = sqv * r2.y + t2.y;
    float m = fmaxf(l0, l1);
    #pragma unroll
    for (int s = 32; s >= 1; s >>= 1) m = fmaxf(m, __shfl_xor(m, s, 64));
    float e0 = __expf(l0 - m), e1 = __expf(l1 - m);
    float sum = e0 + e1;
    #pragma unroll
    for (int w2 = 32; w2 >= 1; w2 >>= 1) sum += __shfl_xor(sum, w2, 64);
    float inv = 1.f / sum;
    float2 o2 = {e0 * inv, e1 * inv};
    *(float2*)&out[row * 128 + lane * 2] = o2;
}

extern "C" void kernel_launch(void* const* d_in, const int* in_sizes, int n_in,
                              void* d_out, int out_size, void* d_ws, size_t ws_size,
                              hipStream_t stream) {
    (void)in_sizes; (void)n_in; (void)out_size; (void)ws_size;
    const float* q      = (const float*)d_in[0];
    const float* k      = (const float*)d_in[1];
    // d_in[2] = scale (unused by reference forward)
    const float* gridv  = (const float*)d_in[3];
    const float* bw     = (const float*)d_in[4];
    const float* coef_q = (const float*)d_in[5];
    const float* coef_k = (const float*)d_in[6];
    const float* sbase  = (const float*)d_in[7];   // scale_base
    const float* ssp    = (const float*)d_in[8];   // scale_sp
    const float* w_qk   = (const float*)d_in[9];
    const float* b_qk   = (const float*)d_in[10];

    float* out  = (float*)d_out;
    float* ws   = (float*)d_ws;
    float* sums = ws;                               // 65536
    float* R    = ws + 65536;                       // 128
    float* T    = ws + 65664;                       // 32768
    unsigned short* wbf = (unsigned short*)(ws + 98432);  // 16384 ushorts

    k_convert<<<64, 256, 0, stream>>>(bw, wbf);
    k_branch<<<512, 512, 0, stream>>>(q, k, wbf, gridv, coef_q, coef_k,
                                      sbase, ssp, sums);
    k_tvec<<<257, 128, 0, stream>>>(sums, w_qk, b_qk, T, R);
    k_softmax<<<32768 / 4, 256, 0, stream>>>(sums, T, R, out);
}

// Round 6
// 69.221 us; speedup vs baseline: 1.0864x; 1.0864x over previous
//
#include <hip/hip_runtime.h>

// Problem: B=16,H=16,P=128,D=128,NF=12
// rows per branch = B*H*P = 32768; total rows (q then k) = 65536.
//
// R6 structure (128-row blocks, 8 waves, 64KB LDS):
//   phase 1: stage W bf16 [128][128]; per-thread (8 rows x 4 cols): load x,
//            silu->A bf16 staging, Chebyshev sin-dot f = (coef . sin(u*x))*ssp
//            kept in registers (native v_sin/v_cos, coef hoisted 12 loads).
//   barrier; phase 2: MFMA (wave: 16 rows x 128 cols); barrier
//   phase 3: acc -> F f32 [128][128] overlaying dead W+A (wave-private rows)
//   phase 4: z = f + F*sbase; sigmoid; 32-lane row reduce. No more barriers.
//
// ws layout (floats):
//   sums: [0, 65536)   R: [65536, 65664)   T: [65664, 98432)
//   wbf:  [98432, ...) base_weight bf16 bits (16384 ushorts)

typedef float          f32x4 __attribute__((ext_vector_type(4)));
typedef short          s16x8 __attribute__((ext_vector_type(8)));
typedef unsigned short u16x8 __attribute__((ext_vector_type(8)));
typedef unsigned short u16x4 __attribute__((ext_vector_type(4)));

static __device__ __forceinline__ unsigned short f2bf(float f) {
    unsigned int u = __float_as_uint(f);
    u += 0x7FFFu + ((u >> 16) & 1u);       // round-to-nearest-even
    return (unsigned short)(u >> 16);
}
// XOR swizzle for [row][256B] bf16 LDS tiles read 16B/lane (G4 pattern)
static __device__ __forceinline__ int swz(int local) {
    return local ^ (((local >> 8) & 7) << 4);
}

__global__ __launch_bounds__(256) void k_convert(const float* __restrict__ bw,
                                                 unsigned short* __restrict__ wbf) {
    int i = blockIdx.x * 256 + threadIdx.x;
    if (i < 128 * 128) wbf[i] = f2bf(bw[i]);
}

__global__ __launch_bounds__(512, 4) void k_branch(
    const float* __restrict__ q, const float* __restrict__ k,
    const unsigned short* __restrict__ wbf,   // base_weight bf16 [d][e] (= B[n][k])
    const float* __restrict__ gridv,          // [12], == 1..12
    const float* __restrict__ coef_q, const float* __restrict__ coef_k,
    const float* __restrict__ sbase,          // scale_base (1,H,P,D)
    const float* __restrict__ ssp,            // scale_sp   (1,H,P,D)
    float* __restrict__ sums)
{
    __shared__ char smem[65536];
    // [0,32768): W bf16 swizzled; [32768,65536): A bf16 swizzled
    // after MFMA: F f32 [128][128] overlays everything
    float* F_l = (float*)smem;

    const int t = threadIdx.x;
    const int lane = t & 63, w = t >> 6;        // 8 waves
    const int r15 = lane & 15, g4 = lane >> 4;  // MFMA fragment coords
    const int c  = t & 31;                      // epilogue col group: cols c*4..+3
    const int rg = t >> 5;                      // epilogue row group: rows rg*8..+7
    const int row0 = blockIdx.x * 128;
    const bool is_q = row0 < 32768;
    const float* X = is_q ? q : k;
    const float* coef = is_q ? coef_q : coef_k;
    const int xrow0 = is_q ? row0 : row0 - 32768;
    const float g1 = gridv[0];                  // == 1.0; freqs are g1*(1..12)

    // ---- phase 1a: stage W bf16 (block-wide, 4 x 16B per thread) ----
    #pragma unroll
    for (int it = 0; it < 4; ++it) {
        int ci = it * 512 + t;                      // 0..2047 chunks
        u16x8 v = *(const u16x8*)&wbf[ci * 8];
        *(u16x8*)(smem + swz(ci * 16)) = v;
    }

    // ---- phase 1b: load x (8 rows x 4 cols), silu -> A staging ----
    float xs[8][4];
    #pragma unroll
    for (int it = 0; it < 8; ++it) {
        int row = rg * 8 + it;
        float4 x4 = *(const float4*)&X[(xrow0 + row) * 128 + c * 4];
        xs[it][0] = x4.x; xs[it][1] = x4.y; xs[it][2] = x4.z; xs[it][3] = x4.w;
        u16x4 sv;
        #pragma unroll
        for (int j = 0; j < 4; ++j) {
            float xv = xs[it][j];
            sv[j] = f2bf(xv / (1.f + __expf(-xv)));
        }
        *(u16x4*)(smem + swz(32768 + row * 256 + c * 8)) = sv;
    }

    // ---- phase 1c: Chebyshev sin-dot, coef hoisted per col (reused 8 rows) ----
    float fv[8][4];
    #pragma unroll
    for (int j = 0; j < 4; ++j) {
        int col = c * 4 + j;
        const float4* cp = (const float4*)&coef[col * 12];
        float4 c0 = cp[0], c1 = cp[1], c2 = cp[2];
        float cf[12] = {c0.x, c0.y, c0.z, c0.w, c1.x, c1.y, c1.z, c1.w,
                        c2.x, c2.y, c2.z, c2.w};
        #pragma unroll
        for (int it = 0; it < 8; ++it) {
            float a = g1 * xs[it][j];
            float s1 = __sinf(a);                   // native v_sin_f32
            float cv = __cosf(a);                   // native v_cos_f32
            float t2 = cv + cv;
            float sprev = 0.f, scur = s1;
            float f = cf[0] * s1;
            #pragma unroll
            for (int u = 1; u < 12; ++u) {
                float snext = __builtin_fmaf(t2, scur, -sprev);
                f = __builtin_fmaf(cf[u], snext, f);
                sprev = scur; scur = snext;
            }
            fv[it][j] = f;
        }
    }
    // fold *ssp (transient float4 per row)
    #pragma unroll
    for (int it = 0; it < 8; ++it) {
        int row = rg * 8 + it;
        int hp = (row0 + row) & 2047;
        float4 sp = *(const float4*)&ssp[hp * 128 + c * 4];
        fv[it][0] *= sp.x; fv[it][1] *= sp.y; fv[it][2] *= sp.z; fv[it][3] *= sp.w;
    }
    __syncthreads();

    // ---- phase 2: MFMA  out[m][n] = sum_k silu(x)[m][k] * W[n][k] ----
    f32x4 acc[8];
    #pragma unroll
    for (int n = 0; n < 8; ++n) acc[n] = (f32x4){0.f, 0.f, 0.f, 0.f};

    const int abase = 32768 + (w * 16 + r15) * 256 + g4 * 16;  // A row = m
    const int bbase = r15 * 256 + g4 * 16;                     // W row = n
    #pragma unroll
    for (int s = 0; s < 4; ++s) {                              // k-steps of 32
        s16x8 af = *(const s16x8*)(smem + swz(abase + s * 64));
        #pragma unroll
        for (int n = 0; n < 8; ++n) {
            s16x8 bf = *(const s16x8*)(smem + swz(bbase + n * 4096 + s * 64));
            acc[n] = __builtin_amdgcn_mfma_f32_16x16x32_bf16(af, bf, acc[n], 0, 0, 0);
        }
    }
    __syncthreads();   // all waves done reading W/A; F may now overlay

    // ---- phase 3: acc -> F_l (wave-private rows w*16..w*16+15) ----
    #pragma unroll
    for (int n = 0; n < 8; ++n) {
        int col = n * 16 + r15;
        #pragma unroll
        for (int reg = 0; reg < 4; ++reg) {
            int row = w * 16 + g4 * 4 + reg;
            F_l[row * 128 + col] = acc[n][reg];
        }
    }
    // no barrier: phase 4 reads only this wave's rows (DS in-order per wave)

    // ---- phase 4: z = f + F*sbase; sigmoid; reduce ----
    #pragma unroll
    for (int it = 0; it < 8; ++it) {
        int row = rg * 8 + it;
        int hp = (row0 + row) & 2047;
        f32x4 F4 = *(f32x4*)&F_l[row * 128 + c * 4];
        float4 sb = *(const float4*)&sbase[hp * 128 + c * 4];
        float sbv[4] = {sb.x, sb.y, sb.z, sb.w};
        float ps = 0.f;
        #pragma unroll
        for (int j = 0; j < 4; ++j) {
            float z = fv[it][j] + F4[j] * sbv[j];
            ps += 1.f / (1.f + __expf(-z));
        }
        // reduce over the 32 lanes (c-groups) sharing this row
        ps += __shfl_xor(ps, 1, 64);
        ps += __shfl_xor(ps, 2, 64);
        ps += __shfl_xor(ps, 4, 64);
        ps += __shfl_xor(ps, 8, 64);
        ps += __shfl_xor(ps, 16, 64);
        if (c == 0) sums[row0 + row] = ps;
    }
}

// T[bh][j] = sum_p sk[bh][p]*w_qk[j][p] + b_qk[j]; block 256 computes R[j].
__global__ __launch_bounds__(128) void k_tvec(
    const float* __restrict__ sums, const float* __restrict__ w_qk,
    const float* __restrict__ b_qk, float* __restrict__ T, float* __restrict__ R)
{
    __shared__ float skl[128];
    int bh = blockIdx.x;
    int t = threadIdx.x;
    const float4* wr = (const float4*)&w_qk[t * 128];
    if (bh < 256) {
        skl[t] = sums[32768 + bh * 128 + t];
        __syncthreads();
        float a = 0.f;
        #pragma unroll 8
        for (int p4 = 0; p4 < 32; ++p4) {
            float4 w4 = wr[p4];
            a += w4.x * skl[p4 * 4 + 0] + w4.y * skl[p4 * 4 + 1] +
                 w4.z * skl[p4 * 4 + 2] + w4.w * skl[p4 * 4 + 3];
        }
        T[bh * 128 + t] = a + b_qk[t];
    } else {
        float a = 0.f;
        #pragma unroll 8
        for (int p4 = 0; p4 < 32; ++p4) {
            float4 w4 = wr[p4];
            a += w4.x + w4.y + w4.z + w4.w;
        }
        R[t] = a;
    }
}

// Softmax over j: logit[j] = sq[row]*R[j] + T[bh][j]. One wave per row.
__global__ __launch_bounds__(256) void k_softmax(
    const float* __restrict__ sums, const float* __restrict__ T,
    const float* __restrict__ R, float* __restrict__ out)
{
    int row = blockIdx.x * 4 + (threadIdx.x >> 6);
    int lane = threadIdx.x & 63;
    int bh = row >> 7;
    float sqv = sums[row];
    float2 r2 = *(const float2*)&R[lane * 2];
    float2 t2 = *(const float2*)&T[bh * 128 + lane * 2];
    float l0 = sqv * r2.x + t2.x;
    float l1 = sqv * r2.y + t2.y;
    float m = fmaxf(l0, l1);
    #pragma unroll
    for (int s = 32; s >= 1; s >>= 1) m = fmaxf(m, __shfl_xor(m, s, 64));
    float e0 = __expf(l0 - m), e1 = __expf(l1 - m);
    float sum = e0 + e1;
    #pragma unroll
    for (int w2 = 32; w2 >= 1; w2 >>= 1) sum += __shfl_xor(sum, w2, 64);
    float inv = 1.f / sum;
    float2 o2 = {e0 * inv, e1 * inv};
    *(float2*)&out[row * 128 + lane * 2] = o2;
}

extern "C" void kernel_launch(void* const* d_in, const int* in_sizes, int n_in,
                              void* d_out, int out_size, void* d_ws, size_t ws_size,
                              hipStream_t stream) {
    (void)in_sizes; (void)n_in; (void)out_size; (void)ws_size;
    const float* q      = (const float*)d_in[0];
    const float* k      = (const float*)d_in[1];
    // d_in[2] = scale (unused by reference forward)
    const float* gridv  = (const float*)d_in[3];
    const float* bw     = (const float*)d_in[4];
    const float* coef_q = (const float*)d_in[5];
    const float* coef_k = (const float*)d_in[6];
    const float* sbase  = (const float*)d_in[7];   // scale_base
    const float* ssp    = (const float*)d_in[8];   // scale_sp
    const float* w_qk   = (const float*)d_in[9];
    const float* b_qk   = (const float*)d_in[10];

    float* out  = (float*)d_out;
    float* ws   = (float*)d_ws;
    float* sums = ws;                               // 65536
    float* R    = ws + 65536;                       // 128
    float* T    = ws + 65664;                       // 32768
    unsigned short* wbf = (unsigned short*)(ws + 98432);  // 16384 ushorts

    k_convert<<<64, 256, 0, stream>>>(bw, wbf);
    k_branch<<<512, 512, 0, stream>>>(q, k, wbf, gridv, coef_q, coef_k,
                                      sbase, ssp, sums);
    k_tvec<<<257, 128, 0, stream>>>(sums, w_qk, b_qk, T, R);
    k_softmax<<<32768 / 4, 256, 0, stream>>>(sums, T, R, out);
}

// Round 7
// 46.680 us; speedup vs baseline: 1.6111x; 1.4829x over previous
//
#include <hip/hip_runtime.h>

// Problem: B=16,H=16,P=128,D=128,NF=12
// rows per branch = B*H*P = 32768; total rows (q then k) = 65536.
//
// R7 structure (128-row blocks, 8 waves, 64KB LDS) — NOTHING per-thread
// survives a barrier except the MFMA accumulator (R3/R6 spill lesson):
//   phase 1: stage W bf16 [128][128] + silu(x) bf16 (transient)
//   barrier; phase 2: MFMA (wave: 16 rows x 128 cols); barrier
//   phase 3: acc -> F f32 [128][128] overlaying dead W+A (wave-private rows)
//   phase 4: per-thread 4 cols x 8 rows: coef hoisted once (48 regs),
//            x re-read (L1), Chebyshev sin-dot w/ native v_sin/v_cos,
//            z = f*ssp + F*sbase, sigmoid, 32-lane row reduce.
//
// ws layout (floats):
//   sums: [0, 65536)   R: [65536, 65664)   T: [65664, 98432)
//   wbf:  [98432, ...) base_weight bf16 bits (16384 ushorts)

typedef float          f32x4 __attribute__((ext_vector_type(4)));
typedef short          s16x8 __attribute__((ext_vector_type(8)));
typedef unsigned short u16x8 __attribute__((ext_vector_type(8)));
typedef unsigned short u16x4 __attribute__((ext_vector_type(4)));

static __device__ __forceinline__ unsigned short f2bf(float f) {
    unsigned int u = __float_as_uint(f);
    u += 0x7FFFu + ((u >> 16) & 1u);       // round-to-nearest-even
    return (unsigned short)(u >> 16);
}
// XOR swizzle for [row][256B] bf16 LDS tiles read 16B/lane (G4 pattern)
static __device__ __forceinline__ int swz(int local) {
    return local ^ (((local >> 8) & 7) << 4);
}

__global__ __launch_bounds__(256) void k_convert(const float* __restrict__ bw,
                                                 unsigned short* __restrict__ wbf) {
    int i = blockIdx.x * 256 + threadIdx.x;
    if (i < 128 * 128) wbf[i] = f2bf(bw[i]);
}

__global__ __launch_bounds__(512, 4) void k_branch(
    const float* __restrict__ q, const float* __restrict__ k,
    const unsigned short* __restrict__ wbf,   // base_weight bf16 [d][e] (= B[n][k])
    const float* __restrict__ gridv,          // [12], == 1..12
    const float* __restrict__ coef_q, const float* __restrict__ coef_k,
    const float* __restrict__ sbase,          // scale_base (1,H,P,D)
    const float* __restrict__ ssp,            // scale_sp   (1,H,P,D)
    float* __restrict__ sums)
{
    __shared__ char smem[65536];
    // [0,32768): W bf16 swizzled; [32768,65536): A bf16 swizzled
    // after MFMA: F f32 [128][128] overlays everything
    float* F_l = (float*)smem;

    const int t = threadIdx.x;
    const int lane = t & 63, w = t >> 6;        // 8 waves
    const int r15 = lane & 15, g4 = lane >> 4;  // MFMA fragment coords
    const int c  = t & 31;                      // epilogue col group: cols c*4..+3
    const int rg = t >> 5;                      // epilogue rows rg*8..+7 (wave-private)
    const int row0 = blockIdx.x * 128;
    const bool is_q = row0 < 32768;
    const float* X = is_q ? q : k;
    const float* coef = is_q ? coef_q : coef_k;
    const int xrow0 = is_q ? row0 : row0 - 32768;
    const float g1 = gridv[0];                  // == 1.0; freqs are g1*(1..12)

    // ---- phase 1a: stage W bf16 (block-wide, 4 x 16B per thread) ----
    #pragma unroll
    for (int it = 0; it < 4; ++it) {
        int ci = it * 512 + t;                      // 0..2047 chunks
        u16x8 v = *(const u16x8*)&wbf[ci * 8];
        *(u16x8*)(smem + swz(ci * 16)) = v;
    }
    // ---- phase 1b: silu(x) -> A staging (transient; x reloaded in phase 4) ----
    #pragma unroll
    for (int it = 0; it < 8; ++it) {
        int row = rg * 8 + it;
        float4 x4 = *(const float4*)&X[(xrow0 + row) * 128 + c * 4];
        float xv[4] = {x4.x, x4.y, x4.z, x4.w};
        u16x4 sv;
        #pragma unroll
        for (int j = 0; j < 4; ++j)
            sv[j] = f2bf(xv[j] / (1.f + __expf(-xv[j])));
        *(u16x4*)(smem + swz(32768 + row * 256 + c * 8)) = sv;
    }
    __syncthreads();

    // ---- phase 2: MFMA  out[m][n] = sum_k silu(x)[m][k] * W[n][k] ----
    f32x4 acc[8];
    #pragma unroll
    for (int n = 0; n < 8; ++n) acc[n] = (f32x4){0.f, 0.f, 0.f, 0.f};

    const int abase = 32768 + (w * 16 + r15) * 256 + g4 * 16;  // A row = m
    const int bbase = r15 * 256 + g4 * 16;                     // W row = n
    #pragma unroll
    for (int s = 0; s < 4; ++s) {                              // k-steps of 32
        s16x8 af = *(const s16x8*)(smem + swz(abase + s * 64));
        #pragma unroll
        for (int n = 0; n < 8; ++n) {
            s16x8 bf = *(const s16x8*)(smem + swz(bbase + n * 4096 + s * 64));
            acc[n] = __builtin_amdgcn_mfma_f32_16x16x32_bf16(af, bf, acc[n], 0, 0, 0);
        }
    }
    __syncthreads();   // all waves done reading W/A; F may now overlay

    // ---- phase 3: acc -> F_l (wave-private rows w*16..w*16+15) ----
    #pragma unroll
    for (int n = 0; n < 8; ++n) {
        int col = n * 16 + r15;
        #pragma unroll
        for (int reg = 0; reg < 4; ++reg) {
            int row = w * 16 + g4 * 4 + reg;
            F_l[row * 128 + col] = acc[n][reg];
        }
    }
    // no barrier: phase 4 reads only this wave's rows (DS in-order per wave)

    // ---- phase 4: coef hoisted once; per row: sin-dot + sigmoid + reduce ----
    float cf[4][12];
    #pragma unroll
    for (int j = 0; j < 4; ++j) {
        const float4* cp = (const float4*)&coef[(c * 4 + j) * 12];
        float4 c0 = cp[0], c1 = cp[1], c2 = cp[2];
        cf[j][0] = c0.x; cf[j][1] = c0.y; cf[j][2]  = c0.z; cf[j][3]  = c0.w;
        cf[j][4] = c1.x; cf[j][5] = c1.y; cf[j][6]  = c1.z; cf[j][7]  = c1.w;
        cf[j][8] = c2.x; cf[j][9] = c2.y; cf[j][10] = c2.z; cf[j][11] = c2.w;
    }

    #pragma unroll
    for (int it = 0; it < 8; ++it) {
        int row = rg * 8 + it;
        int hp = (row0 + row) & 2047;
        float4 x4 = *(const float4*)&X[(xrow0 + row) * 128 + c * 4];   // L1 hit
        f32x4 F4 = *(f32x4*)&F_l[row * 128 + c * 4];
        float4 sp = *(const float4*)&ssp[hp * 128 + c * 4];
        float4 sb = *(const float4*)&sbase[hp * 128 + c * 4];
        float xv[4] = {x4.x, x4.y, x4.z, x4.w};
        float spv[4] = {sp.x, sp.y, sp.z, sp.w};
        float sbv[4] = {sb.x, sb.y, sb.z, sb.w};
        float ps = 0.f;
        #pragma unroll
        for (int j = 0; j < 4; ++j) {
            float a = g1 * xv[j];
            float s1 = __sinf(a);                   // native v_sin_f32
            float cv = __cosf(a);                   // native v_cos_f32
            float t2 = cv + cv;
            float sprev = 0.f, scur = s1;
            float f = cf[j][0] * s1;
            #pragma unroll
            for (int u = 1; u < 12; ++u) {
                float snext = __builtin_fmaf(t2, scur, -sprev);
                f = __builtin_fmaf(cf[j][u], snext, f);
                sprev = scur; scur = snext;
            }
            float z = f * spv[j] + F4[j] * sbv[j];
            ps += 1.f / (1.f + __expf(-z));
        }
        // reduce over the 32 lanes (c-groups) sharing this row
        ps += __shfl_xor(ps, 1, 64);
        ps += __shfl_xor(ps, 2, 64);
        ps += __shfl_xor(ps, 4, 64);
        ps += __shfl_xor(ps, 8, 64);
        ps += __shfl_xor(ps, 16, 64);
        if (c == 0) sums[row0 + row] = ps;
    }
}

// T[bh][j] = sum_p sk[bh][p]*w_qk[j][p] + b_qk[j]; block 256 computes R[j].
__global__ __launch_bounds__(128) void k_tvec(
    const float* __restrict__ sums, const float* __restrict__ w_qk,
    const float* __restrict__ b_qk, float* __restrict__ T, float* __restrict__ R)
{
    __shared__ float skl[128];
    int bh = blockIdx.x;
    int t = threadIdx.x;
    const float4* wr = (const float4*)&w_qk[t * 128];
    if (bh < 256) {
        skl[t] = sums[32768 + bh * 128 + t];
        __syncthreads();
        float a = 0.f;
        #pragma unroll 8
        for (int p4 = 0; p4 < 32; ++p4) {
            float4 w4 = wr[p4];
            a += w4.x * skl[p4 * 4 + 0] + w4.y * skl[p4 * 4 + 1] +
                 w4.z * skl[p4 * 4 + 2] + w4.w * skl[p4 * 4 + 3];
        }
        T[bh * 128 + t] = a + b_qk[t];
    } else {
        float a = 0.f;
        #pragma unroll 8
        for (int p4 = 0; p4 < 32; ++p4) {
            float4 w4 = wr[p4];
            a += w4.x + w4.y + w4.z + w4.w;
        }
        R[t] = a;
    }
}

// Softmax over j: logit[j] = sq[row]*R[j] + T[bh][j]. One wave per row.
__global__ __launch_bounds__(256) void k_softmax(
    const float* __restrict__ sums, const float* __restrict__ T,
    const float* __restrict__ R, float* __restrict__ out)
{
    int row = blockIdx.x * 4 + (threadIdx.x >> 6);
    int lane = threadIdx.x & 63;
    int bh = row >> 7;
    float sqv = sums[row];
    float2 r2 = *(const float2*)&R[lane * 2];
    float2 t2 = *(const float2*)&T[bh * 128 + lane * 2];
    float l0 = sqv * r2.x + t2.x;
    float l1 = sqv * r2.y + t2.y;
    float m = fmaxf(l0, l1);
    #pragma unroll
    for (int s = 32; s >= 1; s >>= 1) m = fmaxf(m, __shfl_xor(m, s, 64));
    float e0 = __expf(l0 - m), e1 = __expf(l1 - m);
    float sum = e0 + e1;
    #pragma unroll
    for (int w2 = 32; w2 >= 1; w2 >>= 1) sum += __shfl_xor(sum, w2, 64);
    float inv = 1.f / sum;
    float2 o2 = {e0 * inv, e1 * inv};
    *(float2*)&out[row * 128 + lane * 2] = o2;
}

extern "C" void kernel_launch(void* const* d_in, const int* in_sizes, int n_in,
                              void* d_out, int out_size, void* d_ws, size_t ws_size,
                              hipStream_t stream) {
    (void)in_sizes; (void)n_in; (void)out_size; (void)ws_size;
    const float* q      = (const float*)d_in[0];
    const float* k      = (const float*)d_in[1];
    // d_in[2] = scale (unused by reference forward)
    const float* gridv  = (const float*)d_in[3];
    const float* bw     = (const float*)d_in[4];
    const float* coef_q = (const float*)d_in[5];
    const float* coef_k = (const float*)d_in[6];
    const float* sbase  = (const float*)d_in[7];   // scale_base
    const float* ssp    = (const float*)d_in[8];   // scale_sp
    const float* w_qk   = (const float*)d_in[9];
    const float* b_qk   = (const float*)d_in[10];

    float* out  = (float*)d_out;
    float* ws   = (float*)d_ws;
    float* sums = ws;                               // 65536
    float* R    = ws + 65536;                       // 128
    float* T    = ws + 65664;                       // 32768
    unsigned short* wbf = (unsigned short*)(ws + 98432);  // 16384 ushorts

    k_convert<<<64, 256, 0, stream>>>(bw, wbf);
    k_branch<<<512, 512, 0, stream>>>(q, k, wbf, gridv, coef_q, coef_k,
                                      sbase, ssp, sums);
    k_tvec<<<257, 128, 0, stream>>>(sums, w_qk, b_qk, T, R);
    k_softmax<<<32768 / 4, 256, 0, stream>>>(sums, T, R, out);
}